// Round 6
// baseline (24.783 us; speedup 1.0000x reference)
//
#include <hip/hip_runtime.h>
#include <math.h>

#define NB 512
#define NK 64
#define NP 25
#define HW 400
#define NC 10

// ---------------- Kernel A: per-(image, row-half) strip minima ----------------
// grid = NB*2 blocks: block (b, rw) covers output rows rw*10..rw*10+9.
// 256 threads = 4 waves; wave cs covers cols cs*5..cs*5+4. lane = k.
__global__ __launch_bounds__(256, 4) void geneo_strip_kernel(
    const float* __restrict__ x,        // (B,1,20,20)
    const float* __restrict__ patterns, // (K,1,5,5)
    float2* __restrict__ ws)            // (NB*2, NK): (smin, bitcast idx)
{
    // 4 pre-shifted copies of the 14 needed padded rows (24 cols each):
    // copy j holds padded col (w0+j) at index w0 -> strip cs reads 16B-aligned
    // float4s at base col cs*4 of copy cs (padded cols cs*5 .. cs*5+8).
    __shared__ __align__(16) float xps[4][14 * 24];
    __shared__ __align__(16) float pat_lds[NK * NP];
    __shared__ float redv[4][NK];
    __shared__ int   redi[4][NK];

    const int tid  = threadIdx.x;
    const int blk  = blockIdx.x;
    const int b    = blk >> 1;
    const int rw   = blk & 1;
    const int lane = tid & 63;
    const int cs   = tid >> 6;          // wave id = col strip

    // ---- stage shifted padded copies of rows [rw*10, rw*10+14) ----
    #pragma unroll
    for (int cp = 0; cp < 4; ++cp) {
        for (int i = tid; i < 14 * 24; i += 256) {
            const int lr = i / 24;            // local padded row
            const int w0 = i - lr * 24;
            const int pr = rw * 10 + lr;      // padded row
            const int pc = w0 + cp;           // padded col
            float v = 0.f;
            if (pr >= 2 && pr < 22 && pc >= 2 && pc < 22)
                v = x[b * HW + (pr - 2) * 20 + (pc - 2)];
            xps[cp][i] = v;
        }
    }
    // ---- stage patterns coalesced (1600 floats = 400 float4) ----
    {
        const float4* p4 = reinterpret_cast<const float4*>(patterns);
        float4*       l4 = reinterpret_cast<float4*>(pat_lds);
        l4[tid] = p4[tid];
        if (tid + 256 < 400) l4[tid + 256] = p4[tid + 256];
    }
    __syncthreads();

    // lane owns pattern k = lane (stride-25 b32: benign 2-way conflicts)
    float patv[NP];
    #pragma unroll
    for (int j = 0; j < NP; ++j) patv[j] = pat_lds[lane * NP + j];

    const float* xbase = &xps[cs][cs * 4];   // local row r at xbase + r*24
    const int col0 = cs * 5;

    float smin = 1e30f;
    int   bi   = 0;
    float Wf[5][9];                          // 45 VGPRs, static-indexed only

    // initial fill: local rows 0..4 -> slots 0..4
    #pragma unroll
    for (int q = 0; q < 5; ++q) {
        const float* rp = xbase + q * 24;
        const float4 a = *reinterpret_cast<const float4*>(rp);
        const float4 c = *reinterpret_cast<const float4*>(rp + 4);
        Wf[q][0] = a.x; Wf[q][1] = a.y; Wf[q][2] = a.z; Wf[q][3] = a.w;
        Wf[q][4] = c.x; Wf[q][5] = c.y; Wf[q][6] = c.z; Wf[q][7] = c.w;
        Wf[q][8] = rp[8];
    }

    #pragma unroll 1
    for (int rr = 0; rr < 2; ++rr) {
        #pragma unroll
        for (int p = 0; p < 5; ++p) {        // 5-phase: slot indices static
            const int i = rr * 5 + p;        // local output row 0..9
            #pragma unroll
            for (int px = 0; px < 5; ++px) {
                float s = 0.f;
                #pragma unroll
                for (int dy = 0; dy < 5; ++dy) {
                    const int slot = (p + dy) % 5;   // compile-time
                    #pragma unroll
                    for (int dx = 0; dx < 5; ++dx)
                        s += fabsf(patv[dy * 5 + dx] - Wf[slot][px + dx]);
                }
                const int pix = (rw * 10 + i) * 20 + col0 + px;
                if (s < smin) { smin = s; bi = pix; }   // strict <: first occ.
            }
            if (i < 9) {                     // retire slot p, load local row i+5
                const float* rp = xbase + (i + 5) * 24;
                const float4 a = *reinterpret_cast<const float4*>(rp);
                const float4 c = *reinterpret_cast<const float4*>(rp + 4);
                Wf[p][0] = a.x; Wf[p][1] = a.y; Wf[p][2] = a.z; Wf[p][3] = a.w;
                Wf[p][4] = c.x; Wf[p][5] = c.y; Wf[p][6] = c.z; Wf[p][7] = c.w;
                Wf[p][8] = rp[8];
            }
        }
    }
    redv[cs][lane] = smin;
    redi[cs][lane] = bi;
    __syncthreads();

    // combine 4 strips, lexicographic (s, idx) min; store per-(blk, k)
    if (tid < NK) {
        float v0 = redv[0][tid];
        int   i0 = redi[0][tid];
        #pragma unroll
        for (int w = 1; w < 4; ++w) {
            const float ov = redv[w][tid];
            const int   oi = redi[w][tid];
            if (ov < v0 || (ov == v0 && oi < i0)) { v0 = ov; i0 = oi; }
        }
        ws[blk * NK + tid] = make_float2(v0, __int_as_float(i0));
    }
}

// ---------------- Kernel B: combine halves + MLP epilogue ----------------
__global__ __launch_bounds__(256) void geneo_out_kernel(
    const float2* __restrict__ ws,      // (NB*2, NK)
    const float* __restrict__ w2,       // (1,K)
    const float* __restrict__ b2,       // (1,)
    const float* __restrict__ wf,       // (NC,400)
    const float* __restrict__ bf,       // (NC,)
    float* __restrict__ out)            // (B,NC)
{
    __shared__ float2 contrib[NK];      // (F*w2, bitcast idx)
    __shared__ float  wsum[4][NC];

    const int tid  = threadIdx.x;
    const int b    = blockIdx.x;
    const int lane = tid & 63;
    const int wave = tid >> 6;

    if (tid < NK) {
        const float2 c0 = ws[(b * 2 + 0) * NK + tid];
        const float2 c1 = ws[(b * 2 + 1) * NK + tid];
        float v0 = c0.x; int i0 = __float_as_int(c0.y);
        const float v1 = c1.x; const int i1 = __float_as_int(c1.y);
        if (v1 < v0 || (v1 == v0 && i1 < i0)) { v0 = v1; i0 = i1; }
        const float F = 1.f - v0 * (1.f / 25.f);
        contrib[tid] = make_float2(F * w2[tid], __int_as_float(i0));
    }
    __syncthreads();

    // sigmoid(scatter + b2) at owned pixels; partial 400->10 dot
    float acc[NC];
    #pragma unroll
    for (int c = 0; c < NC; ++c) acc[c] = 0.f;
    const float b2v = b2[0];

    {
        const int p0 = tid;
        float s = b2v;
        #pragma unroll 8
        for (int k = 0; k < NK; ++k) {
            const float2 cv = contrib[k];
            if (__float_as_int(cv.y) == p0) s += cv.x;
        }
        const float t = 1.f / (1.f + expf(-s));
        #pragma unroll
        for (int c = 0; c < NC; ++c) acc[c] += t * wf[c * HW + p0];
    }
    if (tid + 256 < HW) {
        const int p1 = tid + 256;
        float s = b2v;
        #pragma unroll 8
        for (int k = 0; k < NK; ++k) {
            const float2 cv = contrib[k];
            if (__float_as_int(cv.y) == p1) s += cv.x;
        }
        const float t = 1.f / (1.f + expf(-s));
        #pragma unroll
        for (int c = 0; c < NC; ++c) acc[c] += t * wf[c * HW + p1];
    }

    #pragma unroll
    for (int c = 0; c < NC; ++c) {
        #pragma unroll
        for (int off = 32; off >= 1; off >>= 1)
            acc[c] += __shfl_down(acc[c], off);
    }
    if (lane == 0) {
        #pragma unroll
        for (int c = 0; c < NC; ++c) wsum[wave][c] = acc[c];
    }
    __syncthreads();
    if (tid < NC) {
        const float s = wsum[0][tid] + wsum[1][tid] + wsum[2][tid] + wsum[3][tid] + bf[tid];
        out[b * NC + tid] = 1.f / (1.f + expf(-s));
    }
}

extern "C" void kernel_launch(void* const* d_in, const int* in_sizes, int n_in,
                              void* d_out, int out_size, void* d_ws, size_t ws_size,
                              hipStream_t stream) {
    const float* x        = (const float*)d_in[0];
    const float* patterns = (const float*)d_in[1];
    const float* w2       = (const float*)d_in[2];
    const float* b2       = (const float*)d_in[3];
    const float* wf       = (const float*)d_in[4];
    const float* bf       = (const float*)d_in[5];
    float* out = (float*)d_out;
    float2* ws = (float2*)d_ws;         // NB*2*NK*8B = 512 KB

    geneo_strip_kernel<<<NB * 2, 256, 0, stream>>>(x, patterns, ws);
    geneo_out_kernel<<<NB, 256, 0, stream>>>(ws, w2, b2, wf, bf, out);
}

// Round 7
// 23.093 us; speedup vs baseline: 1.0732x; 1.0732x over previous
//
#include <hip/hip_runtime.h>
#include <math.h>

#define NB 512
#define NK 64
#define NP 25
#define HW 400
#define NC 10

__device__ __forceinline__ unsigned sad16(unsigned a, unsigned b, unsigned c) {
#if __has_builtin(__builtin_amdgcn_sad_u16)
    return __builtin_amdgcn_sad_u16(a, b, c);
#else
    unsigned d;
    asm("v_sad_u16 %0, %1, %2, %3" : "=v"(d) : "v"(a), "v"(b), "v"(c));
    return d;
#endif
}

__global__ void geneo_mlp_kernel(
    const float* __restrict__ x,        // (B,1,20,20)
    const float* __restrict__ patterns, // (K,1,5,5)
    const float* __restrict__ w2,       // (1,K)
    const float* __restrict__ b2,       // (1,)
    const float* __restrict__ wf,       // (NC,400)
    const float* __restrict__ bf,       // (NC,)
    float* __restrict__ out)            // (B,NC)
{
    // Quantized padded image (pad=2, 24x24) and vertical-pair rows:
    //   xq[r][c]  = round(x*65535), zero-extended u16 in u32
    //   pqd[r][c] = xq[r][c] | (xq[r+1][c] << 16)   (r = 0..22)
    __shared__ unsigned xq[24 * 24];
    __shared__ unsigned pqd[23 * 24];
    __shared__ __align__(16) float pat_lds[NK * NP];
    __shared__ unsigned redbest[4][NK];
    __shared__ float2 contrib[NK];      // (F*w2, bitcast idx)
    __shared__ float  wsum[4][NC];

    const int tid  = threadIdx.x;
    const int b    = blockIdx.x;
    const int lane = tid & 63;
    const int wave = tid >> 6;

    // ---- stage quantized padded image + patterns (coalesced) ----
    for (int i = tid; i < 576; i += 256) {
        const int h = i / 24, w = i - h * 24;
        float v = 0.f;
        if (h >= 2 && h < 22 && w >= 2 && w < 22)
            v = x[b * HW + (h - 2) * 20 + (w - 2)];
        xq[i] = (unsigned)(v * 65535.f + 0.5f);
    }
    {
        const float4* p4 = reinterpret_cast<const float4*>(patterns);
        float4*       l4 = reinterpret_cast<float4*>(pat_lds);
        l4[tid] = p4[tid];
        if (tid + 256 < 400) l4[tid + 256] = p4[tid + 256];
    }
    __syncthreads();

    // ---- build vertical-pair rows ----
    for (int i = tid; i < 552; i += 256)
        pqd[i] = xq[i] | (xq[i + 24] << 16);

    // ---- lane owns pattern k = lane: quantize + pack (vertical pairs) ----
    unsigned vp01[5], vp23[5], p4v[5];
    #pragma unroll
    for (int c = 0; c < 5; ++c) {
        const unsigned q0 = (unsigned)(pat_lds[lane * NP +  0 + c] * 65535.f + 0.5f);
        const unsigned q1 = (unsigned)(pat_lds[lane * NP +  5 + c] * 65535.f + 0.5f);
        const unsigned q2 = (unsigned)(pat_lds[lane * NP + 10 + c] * 65535.f + 0.5f);
        const unsigned q3 = (unsigned)(pat_lds[lane * NP + 15 + c] * 65535.f + 0.5f);
        const unsigned q4 = (unsigned)(pat_lds[lane * NP + 20 + c] * 65535.f + 0.5f);
        vp01[c] = q0 | (q1 << 16);
        vp23[c] = q2 | (q3 << 16);
        p4v[c]  = q4;
    }
    __syncthreads();

    // ---- wave = 5-row band (rows wave*5 .. wave*5+4), all 64 k (lane = k) ----
    unsigned best = 0xFFFFFFFFu;        // (s<<9 | pix), min = lexicographic
    const int h0 = wave * 5;

    #pragma unroll 1
    for (int r = 0; r < 5; ++r) {
        const int h = h0 + r;
        #pragma unroll 1
        for (int cb = 0; cb < 4; ++cb) {        // col-blocks of 5 pixels
            const int c0 = cb * 5;
            const unsigned* r01 = &pqd[h * 24 + c0];        // rows h,h+1
            const unsigned* r23 = &pqd[(h + 2) * 24 + c0];  // rows h+2,h+3
            const unsigned* r4  = &xq[(h + 4) * 24 + c0];   // row  h+4
            unsigned W01[9], W23[9], W4[9];
            #pragma unroll
            for (int d = 0; d < 9; ++d) {
                W01[d] = r01[d]; W23[d] = r23[d]; W4[d] = r4[d];
            }
            #pragma unroll
            for (int px = 0; px < 5; ++px) {
                unsigned s = 0;
                #pragma unroll
                for (int dx = 0; dx < 5; ++dx) {
                    s = sad16(W01[px + dx], vp01[dx], s);
                    s = sad16(W23[px + dx], vp23[dx], s);
                    s = sad16(W4 [px + dx], p4v [dx], s);
                }
                const unsigned pk = (s << 9) | (unsigned)(h * 20 + c0 + px);
                best = min(best, pk);
            }
        }
    }
    redbest[wave][lane] = best;
    __syncthreads();

    // ---- combine 4 waves; unpack; contribution = F * w2[k] ----
    if (tid < NK) {
        const unsigned b0 = min(min(redbest[0][tid], redbest[1][tid]),
                                min(redbest[2][tid], redbest[3][tid]));
        const unsigned s  = b0 >> 9;
        const int    pix  = (int)(b0 & 511u);
        const float  F    = 1.f - (float)s * (1.f / (25.f * 65535.f));
        contrib[tid] = make_float2(F * w2[tid], __int_as_float(pix));
    }
    __syncthreads();

    // ---- sigmoid(scatter + b2) at owned pixels; partial 400->10 dot ----
    float acc[NC];
    #pragma unroll
    for (int c = 0; c < NC; ++c) acc[c] = 0.f;
    const float b2v = b2[0];

    {
        const int p0 = tid;
        float s = b2v;
        for (int k = 0; k < NK; ++k) {
            const float2 cv = contrib[k];
            if (__float_as_int(cv.y) == p0) s += cv.x;
        }
        const float t = 1.f / (1.f + expf(-s));
        #pragma unroll
        for (int c = 0; c < NC; ++c) acc[c] += t * wf[c * HW + p0];
    }
    if (tid + 256 < HW) {
        const int p1 = tid + 256;
        float s = b2v;
        for (int k = 0; k < NK; ++k) {
            const float2 cv = contrib[k];
            if (__float_as_int(cv.y) == p1) s += cv.x;
        }
        const float t = 1.f / (1.f + expf(-s));
        #pragma unroll
        for (int c = 0; c < NC; ++c) acc[c] += t * wf[c * HW + p1];
    }

    // ---- block-reduce the 10 class sums ----
    #pragma unroll
    for (int c = 0; c < NC; ++c) {
        #pragma unroll
        for (int off = 32; off >= 1; off >>= 1)
            acc[c] += __shfl_down(acc[c], off);
    }
    if (lane == 0) {
        #pragma unroll
        for (int c = 0; c < NC; ++c) wsum[wave][c] = acc[c];
    }
    __syncthreads();
    if (tid < NC) {
        const float s = wsum[0][tid] + wsum[1][tid] + wsum[2][tid] + wsum[3][tid] + bf[tid];
        out[b * NC + tid] = 1.f / (1.f + expf(-s));
    }
}

extern "C" void kernel_launch(void* const* d_in, const int* in_sizes, int n_in,
                              void* d_out, int out_size, void* d_ws, size_t ws_size,
                              hipStream_t stream) {
    const float* x        = (const float*)d_in[0];
    const float* patterns = (const float*)d_in[1];
    const float* w2       = (const float*)d_in[2];
    const float* b2       = (const float*)d_in[3];
    const float* wf       = (const float*)d_in[4];
    const float* bf       = (const float*)d_in[5];
    float* out = (float*)d_out;

    geneo_mlp_kernel<<<NB, 256, 0, stream>>>(x, patterns, w2, b2, wf, bf, out);
}

// Round 8
// 21.511 us; speedup vs baseline: 1.1521x; 1.0735x over previous
//
#include <hip/hip_runtime.h>
#include <math.h>

#define NB 512
#define NK 64
#define NP 25
#define HW 400
#define NC 10
#define NWAVE 16

__device__ __forceinline__ unsigned sad16(unsigned a, unsigned b, unsigned c) {
#if __has_builtin(__builtin_amdgcn_sad_u16)
    return __builtin_amdgcn_sad_u16(a, b, c);
#else
    unsigned d;
    asm("v_sad_u16 %0, %1, %2, %3" : "=v"(d) : "v"(a), "v"(b), "v"(c));
    return d;
#endif
}

__global__ __launch_bounds__(1024, 4) void geneo_mlp_kernel(
    const float* __restrict__ x,        // (B,1,20,20)
    const float* __restrict__ patterns, // (K,1,5,5)
    const float* __restrict__ w2,       // (1,K)
    const float* __restrict__ b2,       // (1,)
    const float* __restrict__ wf,       // (NC,400)
    const float* __restrict__ bf,       // (NC,)
    float* __restrict__ out)            // (B,NC)
{
    // Quantized padded image (pad=2, 24x24) and vertical-pair rows:
    //   xq[r][c]  = round(x*65535), zero-extended u16 in u32
    //   pqd[r][c] = xq[r][c] | (xq[r+1][c] << 16)   (r = 0..22)
    __shared__ unsigned xq[24 * 24];
    __shared__ unsigned pqd[23 * 24];
    __shared__ __align__(16) float pat_lds[NK * NP];
    __shared__ unsigned redbest[NWAVE][NK];
    __shared__ float2 contrib[NK];      // (F*w2, bitcast idx)
    __shared__ float  wsum[NWAVE][NC];

    const int tid  = threadIdx.x;
    const int b    = blockIdx.x;
    const int lane = tid & 63;
    const int wave = tid >> 6;

    // ---- stage quantized padded image + patterns (1 elem/thread) ----
    if (tid < 576) {
        const int h = tid / 24, w = tid - h * 24;
        float v = 0.f;
        if (h >= 2 && h < 22 && w >= 2 && w < 22)
            v = x[b * HW + (h - 2) * 20 + (w - 2)];
        xq[tid] = (unsigned)(v * 65535.f + 0.5f);
    }
    if (tid < 400)
        reinterpret_cast<float4*>(pat_lds)[tid] =
            reinterpret_cast<const float4*>(patterns)[tid];
    __syncthreads();

    // ---- build vertical-pair rows ----
    if (tid < 552)
        pqd[tid] = xq[tid] | (xq[tid + 24] << 16);

    // ---- lane owns pattern k = lane: quantize + pack (vertical pairs) ----
    unsigned vp01[5], vp23[5], p4v[5];
    #pragma unroll
    for (int c = 0; c < 5; ++c) {
        const unsigned q0 = (unsigned)(pat_lds[lane * NP +  0 + c] * 65535.f + 0.5f);
        const unsigned q1 = (unsigned)(pat_lds[lane * NP +  5 + c] * 65535.f + 0.5f);
        const unsigned q2 = (unsigned)(pat_lds[lane * NP + 10 + c] * 65535.f + 0.5f);
        const unsigned q3 = (unsigned)(pat_lds[lane * NP + 15 + c] * 65535.f + 0.5f);
        const unsigned q4 = (unsigned)(pat_lds[lane * NP + 20 + c] * 65535.f + 0.5f);
        vp01[c] = q0 | (q1 << 16);
        vp23[c] = q2 | (q3 << 16);
        p4v[c]  = q4;
    }
    __syncthreads();

    // ---- wave = tile (tr, tc): rows tr*5..tr*5+4, cols tc*5..tc*5+4 ----
    const int tr = wave >> 2;
    const int tc = wave & 3;
    const int c0 = tc * 5;
    unsigned best = 0xFFFFFFFFu;        // (s<<9 | pix), min = lexicographic

    #pragma unroll 1
    for (int r = 0; r < 5; ++r) {
        const int h = tr * 5 + r;
        const unsigned* r01 = &pqd[h * 24 + c0];        // rows h,h+1
        const unsigned* r23 = &pqd[(h + 2) * 24 + c0];  // rows h+2,h+3
        const unsigned* r4  = &xq[(h + 4) * 24 + c0];   // row  h+4
        unsigned W01[9], W23[9], W4[9];
        #pragma unroll
        for (int d = 0; d < 9; ++d) {
            W01[d] = r01[d]; W23[d] = r23[d]; W4[d] = r4[d];
        }
        #pragma unroll
        for (int px = 0; px < 5; ++px) {
            unsigned s = 0;
            #pragma unroll
            for (int dx = 0; dx < 5; ++dx) {
                s = sad16(W01[px + dx], vp01[dx], s);
                s = sad16(W23[px + dx], vp23[dx], s);
                s = sad16(W4 [px + dx], p4v [dx], s);
            }
            const unsigned pk = (s << 9) | (unsigned)(h * 20 + c0 + px);
            best = min(best, pk);
        }
    }
    redbest[wave][lane] = best;
    __syncthreads();

    // ---- combine 16 waves; unpack; contribution = F * w2[k] ----
    if (tid < NK) {
        unsigned b0 = redbest[0][tid];
        #pragma unroll
        for (int w = 1; w < NWAVE; ++w) b0 = min(b0, redbest[w][tid]);
        const unsigned s  = b0 >> 9;
        const int    pix  = (int)(b0 & 511u);
        const float  F    = 1.f - (float)s * (1.f / (25.f * 65535.f));
        contrib[tid] = make_float2(F * w2[tid], __int_as_float(pix));
    }
    __syncthreads();

    // ---- sigmoid(scatter + b2) at owned pixel; partial 400->10 dot ----
    float acc[NC];
    #pragma unroll
    for (int c = 0; c < NC; ++c) acc[c] = 0.f;

    if (tid < HW) {
        float s = b2[0];
        #pragma unroll 8
        for (int k = 0; k < NK; ++k) {
            const float2 cv = contrib[k];
            if (__float_as_int(cv.y) == tid) s += cv.x;
        }
        const float t = 1.f / (1.f + expf(-s));
        #pragma unroll
        for (int c = 0; c < NC; ++c) acc[c] += t * wf[c * HW + tid];
    }

    // ---- block-reduce the 10 class sums across 16 waves ----
    #pragma unroll
    for (int c = 0; c < NC; ++c) {
        #pragma unroll
        for (int off = 32; off >= 1; off >>= 1)
            acc[c] += __shfl_down(acc[c], off);
    }
    if (lane == 0) {
        #pragma unroll
        for (int c = 0; c < NC; ++c) wsum[wave][c] = acc[c];
    }
    __syncthreads();
    if (tid < NC) {
        float s = bf[tid];
        #pragma unroll
        for (int w = 0; w < NWAVE; ++w) s += wsum[w][tid];
        out[b * NC + tid] = 1.f / (1.f + expf(-s));
    }
}

extern "C" void kernel_launch(void* const* d_in, const int* in_sizes, int n_in,
                              void* d_out, int out_size, void* d_ws, size_t ws_size,
                              hipStream_t stream) {
    const float* x        = (const float*)d_in[0];
    const float* patterns = (const float*)d_in[1];
    const float* w2       = (const float*)d_in[2];
    const float* b2       = (const float*)d_in[3];
    const float* wf       = (const float*)d_in[4];
    const float* bf       = (const float*)d_in[5];
    float* out = (float*)d_out;

    geneo_mlp_kernel<<<NB, 1024, 0, stream>>>(x, patterns, w2, b2, wf, bf, out);
}

// Round 9
// 20.810 us; speedup vs baseline: 1.1909x; 1.0337x over previous
//
#include <hip/hip_runtime.h>
#include <math.h>

#define NB 512
#define NK 64
#define HW 400
#define NC 10

__device__ __forceinline__ unsigned sad16(unsigned a, unsigned b, unsigned c) {
#if __has_builtin(__builtin_amdgcn_sad_u16)
    return __builtin_amdgcn_sad_u16(a, b, c);
#else
    unsigned d;
    asm("v_sad_u16 %0, %1, %2, %3" : "=v"(d) : "v"(a), "v"(b), "v"(c));
    return d;
#endif
}

__global__ __launch_bounds__(1024, 1) void geneo_mlp_kernel(
    const float* __restrict__ x,        // (B,1,20,20)
    const float* __restrict__ patterns, // (K,1,5,5)
    const float* __restrict__ w2,       // (1,K)
    const float* __restrict__ b2,       // (1,)
    const float* __restrict__ wf,       // (NC,400)
    const float* __restrict__ bf,       // (NC,)
    float* __restrict__ out)            // (B,NC)
{
    // xq4[j]: quantized padded image (24x24 u16 in u32), cols shifted by j.
    // pqd4[j]: vertical-pair rows of xq4[j]: row r packs (r lo, r+1 hi).
    // Tile tc (cols tc*5..tc*5+4) reads copy j=tc at word base 4*tc: 16B-aligned.
    __shared__ __align__(16) unsigned xq4[4][576];
    __shared__ __align__(16) unsigned pqd4[4][552];
    __shared__ __align__(16) float pat_lds[NK * 25];
    __shared__ unsigned redbest[16][NK];
    __shared__ float2 pixcv[NK];        // (F*w2, bitcast pix)
    __shared__ float colsum[NC];        // sum_p wf[c,p]
    __shared__ float redout[NC];        // sum_k delta_k * wf[c,pix_k]

    const int tid  = threadIdx.x;
    const int b    = blockIdx.x;
    const int lane = tid & 63;
    const int wave = tid >> 6;

    // ---- A1: quantized padded image (copy 0) + patterns ----
    if (tid < 576) {
        const int h = tid / 24, w = tid - h * 24;
        float v = 0.f;
        if (h >= 2 && h < 22 && w >= 2 && w < 22)
            v = x[b * HW + (h - 2) * 20 + (w - 2)];
        xq4[0][tid] = (unsigned)(v * 65535.f + 0.5f);
    } else if (tid < 976) {
        const int i = tid - 576;      // 400 float4 = 1600 floats
        reinterpret_cast<float4*>(pat_lds)[i] =
            reinterpret_cast<const float4*>(patterns)[i];
    }
    __syncthreads();

    // ---- A2: shifted copies j=1..3 (clamped tail words are never read) ----
    for (int i = tid; i < 3 * 576; i += 1024) {
        const int j = i / 576 + 1;
        const int w = i - (j - 1) * 576;
        int src = w + j; if (src > 575) src = 575;
        xq4[j][w] = xq4[0][src];
    }
    __syncthreads();

    // ---- A3: vertical-pair rows for all 4 copies ----
    for (int i = tid; i < 4 * 552; i += 1024) {
        const int j = i / 552;
        const int w = i - j * 552;
        pqd4[j][w] = xq4[j][w] | (xq4[j][w + 24] << 16);
    }

    // ---- lane owns pattern k = lane: quantize + pack vertical pairs ----
    unsigned vp01[5], vp23[5], p4v[5];
    #pragma unroll
    for (int c = 0; c < 5; ++c) {
        const unsigned q0 = (unsigned)(pat_lds[lane * 25 +  0 + c] * 65535.f + 0.5f);
        const unsigned q1 = (unsigned)(pat_lds[lane * 25 +  5 + c] * 65535.f + 0.5f);
        const unsigned q2 = (unsigned)(pat_lds[lane * 25 + 10 + c] * 65535.f + 0.5f);
        const unsigned q3 = (unsigned)(pat_lds[lane * 25 + 15 + c] * 65535.f + 0.5f);
        const unsigned q4 = (unsigned)(pat_lds[lane * 25 + 20 + c] * 65535.f + 0.5f);
        vp01[c] = q0 | (q1 << 16);
        vp23[c] = q2 | (q3 << 16);
        p4v[c]  = q4;
    }
    __syncthreads();

    // ---- MAIN: wave = tile (tr, tc): rows tr*5.., cols tc*5.. ; lane = k ----
    const int tr   = wave >> 2;
    const int tc   = wave & 3;
    const int base = 4 * tc;            // word base inside copy tc (16B-aligned)
    unsigned best  = 0xFFFFFFFFu;       // (s<<9 | pix): min = lexicographic

    #pragma unroll 1
    for (int r = 0; r < 5; ++r) {
        const int h = tr * 5 + r;
        const unsigned* r01 = &pqd4[tc][h * 24 + base];
        const unsigned* r23 = &pqd4[tc][(h + 2) * 24 + base];
        const unsigned* r4  = &xq4[tc][(h + 4) * 24 + base];
        uint4 A0 = *reinterpret_cast<const uint4*>(r01);
        uint4 A1 = *reinterpret_cast<const uint4*>(r01 + 4);
        unsigned A8 = r01[8];
        uint4 B0 = *reinterpret_cast<const uint4*>(r23);
        uint4 B1 = *reinterpret_cast<const uint4*>(r23 + 4);
        unsigned B8 = r23[8];
        uint4 C0 = *reinterpret_cast<const uint4*>(r4);
        uint4 C1 = *reinterpret_cast<const uint4*>(r4 + 4);
        unsigned C8 = r4[8];
        const unsigned W01[9] = {A0.x, A0.y, A0.z, A0.w, A1.x, A1.y, A1.z, A1.w, A8};
        const unsigned W23[9] = {B0.x, B0.y, B0.z, B0.w, B1.x, B1.y, B1.z, B1.w, B8};
        const unsigned W4 [9] = {C0.x, C0.y, C0.z, C0.w, C1.x, C1.y, C1.z, C1.w, C8};
        #pragma unroll
        for (int px = 0; px < 5; ++px) {
            unsigned s = 0;
            #pragma unroll
            for (int dx = 0; dx < 5; ++dx) {
                s = sad16(W01[px + dx], vp01[dx], s);
                s = sad16(W23[px + dx], vp23[dx], s);
                s = sad16(W4 [px + dx], p4v [dx], s);
            }
            const unsigned pk = (s << 9) | (unsigned)(h * 20 + tc * 5 + px);
            best = min(best, pk);
        }
    }
    redbest[wave][lane] = best;
    __syncthreads();

    // ---- E1 (waves 0-9): colsum[c] = sum_p wf[c,p]  (parallel with E2a) ----
    if (wave < NC) {
        float sc = 0.f;
        for (int p = lane; p < HW; p += 64) sc += wf[wave * HW + p];
        #pragma unroll
        for (int off = 32; off >= 1; off >>= 1) sc += __shfl_down(sc, off);
        if (lane == 0) colsum[wave] = sc;
    }
    // ---- E2a (wave 15): combine 16 tiles per k; pixcv = (F*w2, pix) ----
    if (wave == 15) {
        unsigned b0 = redbest[0][lane];
        #pragma unroll
        for (int w = 1; w < 16; ++w) b0 = min(b0, redbest[w][lane]);
        const float F  = 1.f - (float)(b0 >> 9) * (1.f / (25.f * 65535.f));
        const float cv = F * w2[lane];
        pixcv[lane] = make_float2(cv, __int_as_float((int)(b0 & 511u)));
    }
    __syncthreads();

    // ---- E2b (wave 0): group by pixel, dedupe, 10-class partial ----
    if (wave == 0) {
        const int mypix = __float_as_int(pixcv[lane].y);
        float ssum = 0.f;
        int   firstj = 64;
        #pragma unroll 8
        for (int j = 0; j < NK; ++j) {
            const float2 pc = pixcv[j];
            if (__float_as_int(pc.y) == mypix) {
                ssum += pc.x;
                if (j < firstj) firstj = j;
            }
        }
        const float b2v = b2[0];
        const float t0  = 1.f / (1.f + expf(-b2v));
        const float t   = 1.f / (1.f + expf(-(b2v + ssum)));
        const float dlt = (firstj == lane) ? (t - t0) : 0.f;
        #pragma unroll
        for (int c = 0; c < NC; ++c) {
            float v = dlt * wf[c * HW + mypix];
            #pragma unroll
            for (int off = 32; off >= 1; off >>= 1) v += __shfl_down(v, off);
            if (lane == 0) redout[c] = v;
        }
    }
    __syncthreads();

    // ---- E3: final 10 outputs ----
    if (tid < NC) {
        const float b2v = b2[0];
        const float t0  = 1.f / (1.f + expf(-b2v));
        const float s   = t0 * colsum[tid] + redout[tid] + bf[tid];
        out[b * NC + tid] = 1.f / (1.f + expf(-s));
    }
}

extern "C" void kernel_launch(void* const* d_in, const int* in_sizes, int n_in,
                              void* d_out, int out_size, void* d_ws, size_t ws_size,
                              hipStream_t stream) {
    const float* x        = (const float*)d_in[0];
    const float* patterns = (const float*)d_in[1];
    const float* w2       = (const float*)d_in[2];
    const float* b2       = (const float*)d_in[3];
    const float* wf       = (const float*)d_in[4];
    const float* bf       = (const float*)d_in[5];
    float* out = (float*)d_out;

    geneo_mlp_kernel<<<NB, 1024, 0, stream>>>(x, patterns, w2, b2, wf, bf, out);
}